// Round 4
// baseline (270.588 us; speedup 1.0000x reference)
//
#include <hip/hip_runtime.h>

#define K    5
#define KK   25
#define H    160
#define W    160
#define C    64
#define BS   4
#define HW   (H * W)
#define TX   32          // tile width (pixels)
#define TY   2           // tile height (rows)
#define QX   (TX / 4)    // 8 x-quads per tile row
#define CPG  4           // channels per thread
#define NCG  (C / CPG)   // 16 channel groups
#define BLK  256         // QX * TY * NCG
#define WPAD 36          // padded px stride per tile row in LDS (breaks mod-32 aliasing, keeps 16B align)
#define WSL  (TY * WPAD) // floats per tap slot (72)

// Block = 32x2 pixel tile x ALL 64 channels. Weights for the tile staged in
// LDS once (pre-flipped) -> weight HBM traffic is compulsory 10.2 MB, not
// C/CPG-times re-fetched (R3's FETCH blowup). Thread = 4-px quad x 4 ch;
// per tap-row it batches 5 ds_read_b128 + 16 independent float2 global loads
// before 80 FMAs, so ~16 loads/wave are in flight (R3 had ~2 -> latency-bound).
__global__ __launch_bounds__(BLK, 5) void kconv_kernel(
    const float* __restrict__ fm,
    const float* __restrict__ kern,
    const int*  __restrict__ dil,
    float* __restrict__ out)
{
    __shared__ float wlds[KK][WSL];

    const int tid = threadIdx.x;
    const int b   = blockIdx.z;
    const int x0  = blockIdx.x * TX;
    const int y0  = blockIdx.y * TY;

    // ---- stage per-pixel weights, flipped: slot t holds kern[b][24-t][tile] ----
    const float* kbase = kern + (size_t)b * KK * HW;
    for (int idx = tid; idx < KK * TY * QX; idx += BLK) {   // 400 float4 loads
        const int tap = idx / (TY * QX);                    // memory tap 0..24
        const int rem = idx - tap * (TY * QX);
        const int r   = rem / QX;
        const int c4  = rem - r * QX;
        const float4 v = *(const float4*)(kbase + (size_t)tap * HW +
                                          (size_t)(y0 + r) * W + x0 + c4 * 4);
        *(float4*)&wlds[KK - 1 - tap][r * WPAD + c4 * 4] = v;
    }
    __syncthreads();

    const int qx = tid & (QX - 1);
    const int ty = (tid >> 3) & (TY - 1);
    const int cg = tid >> 4;            // 0..15
    const int x  = x0 + qx * 4;
    const int y  = y0 + ty;
    const int d  = dil[0];

    const float* fb = fm  + ((size_t)b * C + (size_t)cg * CPG) * HW;
    float*       ob = out + ((size_t)b * C + (size_t)cg * CPG) * HW + (size_t)y * W + x;

    if (d == 1) {
        float acc[CPG][4];
#pragma unroll
        for (int c = 0; c < CPG; ++c)
#pragma unroll
            for (int p = 0; p < 4; ++p) acc[c][p] = 0.f;

        // window cols x-2..x+5 as four 8B float2 loads; fully-OOB pair clamped,
        // its consumers all carry zeroed weights.
        const int a_col = (x >= 2) ? (x - 2) : 0;               // clamps only at x==0
        const int d_col = (x + 4 <= W - 2) ? (x + 4) : (W - 2); // clamps only at x==W-4

#pragma unroll
        for (int i = 0; i < K; ++i) {
            const int  yy  = y + i - 2;
            const bool rok = (yy >= 0) && (yy < H);
            const int  yr  = rok ? yy : 0;

            // weights for this tap-row from LDS (already flipped), OOB-zeroed
            float wrow[K][4];
#pragma unroll
            for (int j = 0; j < K; ++j) {
                const float4 wv = *(const float4*)&wlds[i * K + j][ty * WPAD + qx * 4];
                const float wf[4] = {wv.x, wv.y, wv.z, wv.w};
#pragma unroll
                for (int p = 0; p < 4; ++p) {
                    const int col = x + p + j - 2;
                    wrow[j][p] = (rok && col >= 0 && col < W) ? wf[p] : 0.f;
                }
            }

            // batch ALL fm loads for this tap-row (16 independent float2s)
            const float* rowbase = fb + (size_t)yr * W;
            float win[CPG][8];
#pragma unroll
            for (int c = 0; c < CPG; ++c) {
                const float* r = rowbase + (size_t)c * HW;
                const float2 A  = *(const float2*)(r + a_col);
                const float2 Bv = *(const float2*)(r + x);
                const float2 Cv = *(const float2*)(r + x + 2);
                const float2 Dv = *(const float2*)(r + d_col);
                win[c][0] = A.x;  win[c][1] = A.y;
                win[c][2] = Bv.x; win[c][3] = Bv.y;
                win[c][4] = Cv.x; win[c][5] = Cv.y;
                win[c][6] = Dv.x; win[c][7] = Dv.y;
            }

#pragma unroll
            for (int c = 0; c < CPG; ++c)
#pragma unroll
                for (int j = 0; j < K; ++j)
#pragma unroll
                    for (int p = 0; p < 4; ++p)
                        acc[c][p] = fmaf(wrow[j][p], win[c][p + j], acc[c][p]);
        }

#pragma unroll
        for (int c = 0; c < CPG; ++c) {
            const float4 o = {acc[c][0], acc[c][1], acc[c][2], acc[c][3]};
            *(float4*)(ob + (size_t)c * HW) = o;
        }
    } else {
        // Generic-dilation fallback (never taken in this bench; d==1 there).
        const float* kb = kern + (size_t)b * KK * HW + (size_t)y * W + x;
#pragma unroll 1
        for (int p = 0; p < 4; ++p) {
            float wgt[KK];
            int   offs[KK];
#pragma unroll 1
            for (int i = 0; i < K; ++i) {
                const int  yy  = y + (i - 2) * d;
                const bool yok = (yy >= 0) && (yy < H);
                const int  yc  = min(max(yy, 0), H - 1);
#pragma unroll 1
                for (int j = 0; j < K; ++j) {
                    const int  xc  = x + p + (j - 2) * d;
                    const bool ok  = yok && (xc >= 0) && (xc < W);
                    const int  xcc = min(max(xc, 0), W - 1);
                    const int  t   = i * K + j;
                    wgt[t]  = ok ? kb[(size_t)(KK - 1 - t) * HW + p] : 0.f;
                    offs[t] = yc * W + xcc;
                }
            }
#pragma unroll 1
            for (int c = 0; c < CPG; ++c) {
                const float* fc = fb + (size_t)c * HW;
                float a2 = 0.f;
#pragma unroll 1
                for (int t = 0; t < KK; ++t) a2 = fmaf(wgt[t], fc[offs[t]], a2);
                ob[(size_t)c * HW + p] = a2;
            }
        }
    }
}

extern "C" void kernel_launch(void* const* d_in, const int* in_sizes, int n_in,
                              void* d_out, int out_size, void* d_ws, size_t ws_size,
                              hipStream_t stream)
{
    const float* fm   = (const float*)d_in[0];
    const float* kern = (const float*)d_in[1];
    const int*   dil  = (const int*)d_in[2];
    float*       out  = (float*)d_out;

    dim3 grid(W / TX, H / TY, BS);   // 5 x 80 x 4 = 1600 blocks
    kconv_kernel<<<grid, dim3(BLK), 0, stream>>>(fm, kern, dil, out);
}

// Round 5
// 107.565 us; speedup vs baseline: 2.5156x; 2.5156x over previous
//
#include <hip/hip_runtime.h>

#define K   5
#define KK  25
#define H   160
#define W   160
#define C   64
#define BS  4
#define HW  (H * W)
#define CPG 4           // channels per thread (grid.y = C/CPG)
#define BLK 256

// Each thread: one 4-pixel x-quad, CPG channels.
// out[b,c,y,x] = sum_{i,j} kernel[b, 24-(i*5+j), y, x] * fm[b,c,y+i-2,x+j-2] (zero pad)
//
// CPG=4: 1600 blocks = 6400 waves = 25 waves/CU (R2's CPG=8 gave only 12.5 -> latency-bound).
// NO min-waves launch_bounds: R3 (=this kernel + bounds(256,6)) got VGPR capped at 40 and
// R4 (bounds(256,5)) at 48 -> load batches serialized / spilled (WRITE 337 MB). The whole
// design depends on ~100 VGPRs holding 16 in-flight float2 fm loads + 20 weights + 16 acc.
__global__ __launch_bounds__(BLK) void kconv_kernel(
    const float* __restrict__ fm,
    const float* __restrict__ kern,
    const int*  __restrict__ dil,
    float* __restrict__ out)
{
    const int q  = blockIdx.x * BLK + threadIdx.x;   // quad id in [0, HW/4)
    const int b  = blockIdx.z;
    const int cg = blockIdx.y;
    const int d  = dil[0];

    const int y = q / (W / 4);
    const int x = (q - y * (W / 4)) * 4;             // quad start column (mult of 4)

    const float* fb = fm  + ((size_t)b * C + (size_t)cg * CPG) * HW;
    float*       ob = out + ((size_t)b * C + (size_t)cg * CPG) * HW + (size_t)y * W + x;
    const float* kb = kern + (size_t)b * KK * HW + (size_t)y * W + x;

    if (d == 1) {
        float acc[CPG][4];
#pragma unroll
        for (int c = 0; c < CPG; ++c)
#pragma unroll
            for (int p = 0; p < 4; ++p) acc[c][p] = 0.f;

        // Window columns x-2..x+5 as four 8B-aligned float2 loads.
        // Only the fully-OOB pair at the extreme quads gets clamped; every
        // consumer of those window slots has a zeroed weight.
        const int a_col = (x >= 2) ? (x - 2) : 0;               // clamps only at x==0
        const int d_col = (x + 4 <= W - 2) ? (x + 4) : (W - 2); // clamps only at x==W-4

#pragma unroll
        for (int i = 0; i < K; ++i) {
            const int  yy  = y + i - 2;
            const bool rok = (yy >= 0) && (yy < H);
            const int  yr  = rok ? yy : 0;

            // weights for this tap-row (flipped), zeroed where the tap is OOB
            float wrow[K][4];
#pragma unroll
            for (int j = 0; j < K; ++j) {
                const int t = i * K + j;
                const float4 wv = *(const float4*)(kb + (size_t)(KK - 1 - t) * HW);
                const float wf[4] = {wv.x, wv.y, wv.z, wv.w};
#pragma unroll
                for (int p = 0; p < 4; ++p) {
                    const int col = x + p + j - 2;
                    const bool ok = rok && (col >= 0) && (col < W);
                    wrow[j][p] = ok ? wf[p] : 0.f;
                }
            }

            // batch ALL fm loads for this tap-row (16 independent float2s in flight)
            const float* rowbase = fb + (size_t)yr * W;
            float win[CPG][8];
#pragma unroll
            for (int c = 0; c < CPG; ++c) {
                const float* r = rowbase + (size_t)c * HW;
                const float2 A  = *(const float2*)(r + a_col);
                const float2 Bv = *(const float2*)(r + x);
                const float2 Cv = *(const float2*)(r + x + 2);
                const float2 Dv = *(const float2*)(r + d_col);
                win[c][0] = A.x;  win[c][1] = A.y;
                win[c][2] = Bv.x; win[c][3] = Bv.y;
                win[c][4] = Cv.x; win[c][5] = Cv.y;
                win[c][6] = Dv.x; win[c][7] = Dv.y;
            }

#pragma unroll
            for (int c = 0; c < CPG; ++c)
#pragma unroll
                for (int j = 0; j < K; ++j)
#pragma unroll
                    for (int p = 0; p < 4; ++p)
                        acc[c][p] = fmaf(wrow[j][p], win[c][p + j], acc[c][p]);
        }

#pragma unroll
        for (int c = 0; c < CPG; ++c) {
            const float4 o = {acc[c][0], acc[c][1], acc[c][2], acc[c][3]};
            *(float4*)(ob + (size_t)c * HW) = o;
        }
    } else {
        // Generic-dilation fallback (never taken in this bench; d==1 there).
#pragma unroll 1
        for (int p = 0; p < 4; ++p) {
            const int xx = x + p;
            float wgt[KK];
            int   offs[KK];
#pragma unroll 1
            for (int i = 0; i < K; ++i) {
                const int  yy  = y + (i - 2) * d;
                const bool yok = (yy >= 0) && (yy < H);
                const int  yc  = min(max(yy, 0), H - 1);
#pragma unroll 1
                for (int j = 0; j < K; ++j) {
                    const int  xc  = xx + (j - 2) * d;
                    const bool ok  = yok && (xc >= 0) && (xc < W);
                    const int  xcc = min(max(xc, 0), W - 1);
                    const int  t   = i * K + j;
                    wgt[t]  = ok ? kb[(size_t)(KK - 1 - t) * HW + p] : 0.f;
                    offs[t] = yc * W + xcc;
                }
            }
#pragma unroll 1
            for (int c = 0; c < CPG; ++c) {
                const float* fc = fb + (size_t)c * HW;
                float a2 = 0.f;
#pragma unroll 1
                for (int t = 0; t < KK; ++t) a2 = fmaf(wgt[t], fc[offs[t]], a2);
                ob[(size_t)c * HW + p] = a2;
            }
        }
    }
}

extern "C" void kernel_launch(void* const* d_in, const int* in_sizes, int n_in,
                              void* d_out, int out_size, void* d_ws, size_t ws_size,
                              hipStream_t stream)
{
    const float* fm   = (const float*)d_in[0];
    const float* kern = (const float*)d_in[1];
    const int*   dil  = (const int*)d_in[2];
    float*       out  = (float*)d_out;

    dim3 grid(HW / 4 / BLK, C / CPG, BS);   // 25 x 16 x 4 = 1600 blocks
    kconv_kernel<<<grid, dim3(BLK), 0, stream>>>(fm, kern, dil, out);
}